// Round 6
// baseline (216.057 us; speedup 1.0000x reference)
//
#include <hip/hip_runtime.h>
#include <stdint.h>

#define D_MODEL 1024
#define S_LEN   2048
#define BATCH   2
#define NHEAD   16
#define DHEAD   64
#define NTOK    (BATCH * S_LEN)   // 4096

typedef unsigned short u16;
typedef __attribute__((ext_vector_type(8))) short bf16x8;
typedef __attribute__((ext_vector_type(4))) float f32x4;
typedef __attribute__((ext_vector_type(16))) float f32x16;
typedef __attribute__((ext_vector_type(2))) unsigned int u32x2;

__device__ __forceinline__ unsigned pack2bf(float lo, float hi) {
    unsigned a = __float_as_uint(lo) + 0x8000u;
    unsigned b = __float_as_uint(hi) + 0x8000u;
    return __builtin_amdgcn_perm(b, a, 0x07060302u);  // lo16=bf16(lo), hi16=bf16(hi)
}
__device__ __forceinline__ u16 f2bf1(float f) {
    return (u16)((__float_as_uint(f) + 0x8000u) >> 16);
}

#define GAS(p) ((const __attribute__((address_space(1))) void*)(p))
#define LAS(p) ((__attribute__((address_space(3))) void*)(p))
// chunk-XOR swizzled flat [rows][64] bf16 tile: u16 index of (row, chunk-col c)
#define SWZ8(row, c) (((((row) << 3) | ((c) ^ ((row) & 7)))) << 3)

// ---------------------------------------------------------------------------
// convert: fp32 -> bf16 for Q,K,V (4M each) and Wq,Wk,Wv,Wo (1M each).
// ---------------------------------------------------------------------------
__global__ __launch_bounds__(256) void convert_kernel(
    const float* __restrict__ Q, const float* __restrict__ K, const float* __restrict__ V,
    const float* __restrict__ Wq, const float* __restrict__ Wk,
    const float* __restrict__ Wv, const float* __restrict__ Wo,
    u16* __restrict__ Qb, u16* __restrict__ Kb, u16* __restrict__ Vb,
    u16* __restrict__ Wqb, u16* __restrict__ Wkb, u16* __restrict__ Wvb, u16* __restrict__ Wob)
{
    const size_t SEG = 262144;  // float4 per 1M-float quarter
    size_t start = (size_t)blockIdx.x * 4096;
    int s = (int)(start / SEG);
    const float* src; u16* dst; size_t seg0;
    if (s < 4)       { src = Q;  dst = Qb;  seg0 = 0; }
    else if (s < 8)  { src = K;  dst = Kb;  seg0 = 4 * SEG; }
    else if (s < 12) { src = V;  dst = Vb;  seg0 = 8 * SEG; }
    else if (s == 12){ src = Wq; dst = Wqb; seg0 = 12 * SEG; }
    else if (s == 13){ src = Wk; dst = Wkb; seg0 = 13 * SEG; }
    else if (s == 14){ src = Wv; dst = Wvb; seg0 = 14 * SEG; }
    else             { src = Wo; dst = Wob; seg0 = 15 * SEG; }
    size_t off = start - seg0 + threadIdx.x;
    const float4* s4 = (const float4*)src;
    #pragma unroll
    for (int k = 0; k < 16; ++k) {
        float4 x = s4[off + (size_t)k * 256];
        u32x2 p = (u32x2){pack2bf(x.x, x.y), pack2bf(x.z, x.w)};
        *(u32x2*)(dst + (off + (size_t)k * 256) * 4) = p;
    }
}

// ---------------------------------------------------------------------------
// proj: all three projections in ONE launch. 256x256 tile, BK=64, 8 waves
// (2M x 4N), mfma_f32_32x32x16_bf16, double-buffered LDS (128 KB) with one
// raw s_barrier + vmcnt(0) per K-tile; next tile's global_load_lds issued
// right after the barrier so loads fly across a full compute section.
// (R2 structure, measured 46.1 us — R3/R4 scheduling variants both
// regressed; at 1 block/CU this is the local optimum. DO NOT TOUCH.)
// XCD-chunked bijective swizzle (192 blocks = 24/XCD).
// Operand-swapped: A = W (m = dout), B = X (n = token).
//  z=0: qw[tok][dm] = (Qb@Wq^T + bq) * 0.125*log2(e)
//  z=1: kw[tok][dm] =  Kb@Wk^T + bk
//  z=2: vtw[dout][tok] = Wv@Vb^T + bv   (kv-contiguous rows for attention)
// ---------------------------------------------------------------------------
__global__ __launch_bounds__(512, 2) void proj_kernel(
    const u16* __restrict__ Qb, const u16* __restrict__ Kb, const u16* __restrict__ Vb,
    const u16* __restrict__ Wqb, const u16* __restrict__ Wkb, const u16* __restrict__ Wvb,
    const float* __restrict__ bq, const float* __restrict__ bk, const float* __restrict__ bv,
    u16* __restrict__ qw, u16* __restrict__ kw, u16* __restrict__ vtw)
{
    // 192 blocks total; bid%8 round-robins XCDs -> chunk 24 consecutive works/XCD
    const int bid = blockIdx.x;
    const int wid = (bid & 7) * 24 + (bid >> 3);
    const int z = wid >> 6;          // 0..2
    const int r = wid & 63;          // 0..63
    const int nbase = (r >> 2) * 256;   // token   (16 n-tiles)
    const int mbase = (r & 3) * 256;    // dout    (4 m-tiles)

    const u16* Ag = (z == 0) ? Wqb : (z == 1) ? Wkb : Wvb;   // [dout][din]
    const u16* Bg = (z == 0) ? Qb  : (z == 1) ? Kb  : Vb;    // [tok][din]
    const float* bias = (z == 0) ? bq : (z == 1) ? bk : bv;  // indexed by dout

    const int tid = threadIdx.x, lane = tid & 63, wave = tid >> 6;
    const int l31 = lane & 31, hh = lane >> 5;
    const int wm = wave >> 2;        // 0..1  -> 128 dout rows
    const int wn = wave & 3;         // 0..3  -> 64 tokens

    // LDS: A[2][256*64] at 0, B[2][256*64] at 32768 (u16 units). 128 KB total.
    __shared__ __align__(16) u16 smem[65536];

    // staging: 32 segments of 1 KB per matrix; wave w owns segs w*4..w*4+3.
    // chunkpos = seg*64 + lane; row = chunkpos>>3; chunk-col = (chunkpos&7)^(row&7)
    size_t aoff[4], boff[4];
    #pragma unroll
    for (int c = 0; c < 4; ++c) {
        int p = (wave * 4 + c) * 64 + lane;
        int row = p >> 3;
        int cg  = (p & 7) ^ (row & 7);
        aoff[c] = (size_t)(mbase + row) * D_MODEL + cg * 8;
        boff[c] = (size_t)(nbase + row) * D_MODEL + cg * 8;
    }

#define STAGE(buf, kc)                                                              \
    do {                                                                            \
        _Pragma("unroll")                                                           \
        for (int c = 0; c < 4; ++c) {                                               \
            __builtin_amdgcn_global_load_lds(GAS(Ag + aoff[c] + (kc)),              \
                LAS(smem + (buf) * 16384 + (wave * 4 + c) * 512), 16, 0, 0);        \
            __builtin_amdgcn_global_load_lds(GAS(Bg + boff[c] + (kc)),              \
                LAS(smem + 32768 + (buf) * 16384 + (wave * 4 + c) * 512), 16, 0, 0);\
        }                                                                           \
    } while (0)

    STAGE(0, 0);

    f32x16 acc[4][2];
    #pragma unroll
    for (int mt = 0; mt < 4; ++mt)
        #pragma unroll
        for (int nt = 0; nt < 2; ++nt)
            #pragma unroll
            for (int q = 0; q < 16; ++q) acc[mt][nt][q] = 0.f;

    for (int t = 0; t < D_MODEL / 64; ++t) {
        const int cur = t & 1;
        // wait own stage loads of tile t (flew across previous compute section)
        asm volatile("s_waitcnt vmcnt(0) lgkmcnt(0)" ::: "memory");
        __builtin_amdgcn_s_barrier();
        asm volatile("" ::: "memory");
        if (t < D_MODEL / 64 - 1) STAGE(cur ^ 1, (t + 1) * 64);
        const u16* Ab = smem + cur * 16384;
        const u16* Bb = smem + 32768 + cur * 16384;
        #pragma unroll
        for (int kk = 0; kk < 4; ++kk) {
            bf16x8 af[4], bfr[2];
            #pragma unroll
            for (int mt = 0; mt < 4; ++mt)
                af[mt] = *(const bf16x8*)&Ab[SWZ8(wm * 128 + mt * 32 + l31, kk * 2 + hh)];
            #pragma unroll
            for (int nt = 0; nt < 2; ++nt)
                bfr[nt] = *(const bf16x8*)&Bb[SWZ8(wn * 64 + nt * 32 + l31, kk * 2 + hh)];
            #pragma unroll
            for (int mt = 0; mt < 4; ++mt)
                #pragma unroll
                for (int nt = 0; nt < 2; ++nt)
                    acc[mt][nt] = __builtin_amdgcn_mfma_f32_32x32x16_bf16(af[mt], bfr[nt], acc[mt][nt], 0, 0, 0);
        }
    }
#undef STAGE

    // C layout (32x32x16): col(token) = lane&31, row(dout) = (reg&3)+8*(reg>>2)+4*hh
    if (z < 2) {
        u16* Y = z ? kw : qw;
        const float scale = z ? 1.0f : 0.18033688011112042f;  // 0.125*log2(e)
        #pragma unroll
        for (int mt = 0; mt < 4; ++mt)
            #pragma unroll
            for (int nt = 0; nt < 2; ++nt) {
                const int tok = nbase + wn * 64 + nt * 32 + l31;
                u16* yrow = Y + (size_t)tok * D_MODEL;
                #pragma unroll
                for (int g = 0; g < 4; ++g) {
                    const int d0 = mbase + wm * 128 + mt * 32 + 8 * g + 4 * hh;
                    float4 b4 = *(const float4*)&bias[d0];
                    float v0 = (acc[mt][nt][4 * g + 0] + b4.x) * scale;
                    float v1 = (acc[mt][nt][4 * g + 1] + b4.y) * scale;
                    float v2 = (acc[mt][nt][4 * g + 2] + b4.z) * scale;
                    float v3 = (acc[mt][nt][4 * g + 3] + b4.w) * scale;
                    *(u32x2*)(yrow + d0) = (u32x2){pack2bf(v0, v1), pack2bf(v2, v3)};
                }
            }
    } else {
        #pragma unroll
        for (int mt = 0; mt < 4; ++mt)
            #pragma unroll
            for (int nt = 0; nt < 2; ++nt) {
                const int tok = nbase + wn * 64 + nt * 32 + l31;
                #pragma unroll
                for (int g = 0; g < 4; ++g) {
                    const int d0 = mbase + wm * 128 + mt * 32 + 8 * g + 4 * hh;
                    #pragma unroll
                    for (int q = 0; q < 4; ++q)
                        vtw[(size_t)(d0 + q) * NTOK + tok] =
                            f2bf1(acc[mt][nt][4 * g + q] + bias[d0 + q]);
                }
            }
    }
}

// ---------------------------------------------------------------------------
// Flash attention, 512-thread blocks: 8 waves = 4 q-tiles(32q) x 2 kv-halves.
// Each wave: QK (A=K half, B=Q tile) 4 MFMA -> exp2 -> permlane32_swap ->
// PV (A=V^T, B=P^T) 4 MFMA. P packing via v_cvt_pk_bf16_f32 (1 instr/pair);
// cross-half exchange via v_permlane32_swap_b32 (VALU crossbar, no LDS —
// one swap yields BOTH P-frag words: a'={a.lo,b.lo}, b'={a.hi,b.hi}).
// s_setprio(1) around MFMA clusters (T5). Fixed-max exp2 softmax.
// ---------------------------------------------------------------------------
__global__ __launch_bounds__(512, 4) void attn_kernel(
    const u16* __restrict__ qw, const u16* __restrict__ kw,
    const u16* __restrict__ vtw, u16* __restrict__ aw)
{
    const int qbase = blockIdx.x * 128;
    const int h = blockIdx.y, b = blockIdx.z;
    const int tid = threadIdx.x, lane = tid & 63, wave = tid >> 6;
    const int wq = wave & 3;        // q-tile (32 q rows)
    const int wk = wave >> 2;       // kv half (32 kv rows of the 64-tile)
    const int l31 = lane & 31;
    const int hh  = lane >> 5;
    const int colbase = h * DHEAD;
    const size_t qrow0 = (size_t)b * S_LEN + qbase;

    // smem layout (u16 offsets): Ks[buf] at buf*4096, Vs[buf] at 8192+buf*4096;
    // after the kv loop the same region is reused as Ored [4][32][68] f32 +
    // Lred [4][32] f32 at u16 offset 17408. Total 17664 u16 = 35328 B.
    __shared__ __align__(16) u16 smem[17664];
    #define KS_OFF(buf) ((buf) * 4096)
    #define VS_OFF(buf) (8192 + (buf) * 4096)

    // staging: one chunk per thread (512 chunks per 64x64 tile)
    const int srow = tid >> 3;
    const int scg  = (tid & 7) ^ (srow & 7);
    const size_t ksrc = ((size_t)b * S_LEN + srow) * D_MODEL + colbase + scg * 8;
    const size_t vsrc = (size_t)(colbase + srow) * NTOK + (size_t)b * S_LEN + scg * 8;

    #define STAGE_KV(buf, kv0)                                                         \
        do {                                                                           \
            __builtin_amdgcn_global_load_lds(GAS(kw + ksrc + (size_t)(kv0) * D_MODEL), \
                                             LAS(smem + KS_OFF(buf) + wave * 512), 16, 0, 0); \
            __builtin_amdgcn_global_load_lds(GAS(vtw + vsrc + (kv0)),                  \
                                             LAS(smem + VS_OFF(buf) + wave * 512), 16, 0, 0); \
        } while (0)

    // Q B-frags, register-resident: B[k=d=16s+8hh+j][n=q=l31]
    bf16x8 qf[4];
    {
        const u16* qptr = qw + (qrow0 + wq * 32 + l31) * D_MODEL + colbase + hh * 8;
        #pragma unroll
        for (int s = 0; s < 4; ++s) qf[s] = *(const bf16x8*)(qptr + s * 16);
    }

    STAGE_KV(0, 0);

    f32x16 o[2];
    #pragma unroll
    for (int dt = 0; dt < 2; ++dt)
        #pragma unroll
        for (int r = 0; r < 16; ++r) o[dt][r] = 0.f;
    float l = 0.f;

    __syncthreads();

    for (int t = 0; t < S_LEN / 64; ++t) {
        const int cur = t & 1;
        if (t + 1 < S_LEN / 64) STAGE_KV(!cur, (t + 1) * 64);   // prefetch in flight

        // S^T (this wave's 32 kv rows x 32 q cols), C init -12 (exp2 headroom)
        f32x16 sc;
        #pragma unroll
        for (int r = 0; r < 16; ++r) sc[r] = -12.f;
        __builtin_amdgcn_s_setprio(1);
        #pragma unroll
        for (int s = 0; s < 4; ++s) {
            bf16x8 kf = *(const bf16x8*)&smem[KS_OFF(cur) + SWZ8(wk * 32 + l31, s * 2 + hh)];
            sc = __builtin_amdgcn_mfma_f32_32x32x16_bf16(kf, qf[s], sc, 0, 0, 0);
        }
        __builtin_amdgcn_s_setprio(0);

        // p = exp2(s); x[g] covers kv_local = 8g + 4hh + {0..3}
        // v_cvt_pk_bf16_f32: 1 instr packs 2 f32 -> 2 bf16 (no builtin; asm)
        unsigned x[4][2];
        #pragma unroll
        for (int g = 0; g < 4; ++g) {
            float p0 = __builtin_amdgcn_exp2f(sc[4 * g + 0]);
            float p1 = __builtin_amdgcn_exp2f(sc[4 * g + 1]);
            float p2 = __builtin_amdgcn_exp2f(sc[4 * g + 2]);
            float p3 = __builtin_amdgcn_exp2f(sc[4 * g + 3]);
            l += (p0 + p1) + (p2 + p3);
            asm("v_cvt_pk_bf16_f32 %0, %1, %2" : "=v"(x[g][0]) : "v"(p0), "v"(p1));
            asm("v_cvt_pk_bf16_f32 %0, %1, %2" : "=v"(x[g][1]) : "v"(p2), "v"(p3));
        }

        // PV: B-frag(sp) covers kv_local = 16sp + 8hh + j.
        // pf.u[w] needs {lo lanes: x[ge][w&1].row0, hi lanes: x[go][w&1].row0}
        // (w<2) and row1 halves (w>=2) — exactly the two outputs of one
        // v_permlane32_swap_b32 (swaps row1(a) <-> row0(b)).
        #pragma unroll
        for (int sp = 0; sp < 2; ++sp) {
            unsigned a0 = x[2 * sp][0], b0 = x[2 * sp + 1][0];
            unsigned a1 = x[2 * sp][1], b1 = x[2 * sp + 1][1];
            asm("v_permlane32_swap_b32 %0, %1" : "+v"(a0), "+v"(b0));
            asm("v_permlane32_swap_b32 %0, %1" : "+v"(a1), "+v"(b1));
            union { unsigned u[4]; bf16x8 v; } pf;
            pf.u[0] = a0; pf.u[1] = a1; pf.u[2] = b0; pf.u[3] = b1;
            __builtin_amdgcn_s_setprio(1);
            #pragma unroll
            for (int dt = 0; dt < 2; ++dt) {
                bf16x8 vf = *(const bf16x8*)&smem[VS_OFF(cur) + SWZ8(dt * 32 + l31, wk * 4 + sp * 2 + hh)];
                o[dt] = __builtin_amdgcn_mfma_f32_32x32x16_bf16(vf, pf.v, o[dt], 0, 0, 0);
            }
            __builtin_amdgcn_s_setprio(0);
        }

        __syncthreads();   // drains prefetch + protects both staging buffers
    }

    // merge lane halves of l (each covers complementary kv groups)
    l += __shfl_xor(l, 32);

    // cross kv-half reduction through LDS (staging region is dead now)
    float* Ored = (float*)smem;                   // [4 qt][32 q][68] f32
    float* Lred = (float*)(smem + 17408);         // [4 qt][32 q] f32
    float* op = Ored + ((size_t)wq * 32 + l31) * 68;
    if (wk == 1) {
        #pragma unroll
        for (int dt = 0; dt < 2; ++dt)
            #pragma unroll
            for (int g = 0; g < 4; ++g)
                *(f32x4*)(op + dt * 32 + 8 * g + 4 * hh) =
                    (f32x4){o[dt][4 * g + 0], o[dt][4 * g + 1], o[dt][4 * g + 2], o[dt][4 * g + 3]};
        if (hh == 0) Lred[wq * 32 + l31] = l;
    }
    __syncthreads();
    if (wk == 0) {
        l += Lred[wq * 32 + l31];
        float inv = 1.0f / l;
        size_t orow = (qrow0 + wq * 32 + l31) * D_MODEL + colbase;
        #pragma unroll
        for (int dt = 0; dt < 2; ++dt)
            #pragma unroll
            for (int g = 0; g < 4; ++g) {
                f32x4 add = *(const f32x4*)(op + dt * 32 + 8 * g + 4 * hh);
                float v0 = (o[dt][4 * g + 0] + add[0]) * inv;
                float v1 = (o[dt][4 * g + 1] + add[1]) * inv;
                float v2 = (o[dt][4 * g + 2] + add[2]) * inv;
                float v3 = (o[dt][4 * g + 3] + add[3]) * inv;
                *(u32x2*)(aw + orow + dt * 32 + 8 * g + 4 * hh) =
                    (u32x2){pack2bf(v0, v1), pack2bf(v2, v3)};
            }
    }
    #undef STAGE_KV
    #undef KS_OFF
    #undef VS_OFF
}

// ---------------------------------------------------------------------------
// outproj: out[tok][dm] = aw @ Wo^T + bo (fp32 out). R6: BK=128 -> only 8
// serial {drain -> stage -> compute} K-iterations (R5 had 16; at 1 block/CU
// the per-iteration drain is the critical path, so halving the count halves
// the serial tax while doubling per-iter compute cover). 128x128 tile,
// 256 blocks (1/CU), 512 threads / 8 waves (2M x 4N), 32x32x16 MFMA.
// LDS 128 KB: per buf, each matrix's 128x128 K-tile is stored as TWO 64-col
// subtiles, each with the proven SWZ8 layout (kk 0..3 -> sub 0, 4..7 ->
// sub 1); staged linearly with pre-inverse-swizzled source (rule #21).
// XCD-chunked: 32 consecutive works/XCD -> Wo + aw panels L2-resident.
// Operand-swapped: A = Wo (m = dout), B = aw (n = token).
// ---------------------------------------------------------------------------
__global__ __launch_bounds__(512, 2) void outproj_kernel(
    const u16* __restrict__ aw, const u16* __restrict__ Wob,
    const float* __restrict__ bo, float* __restrict__ out)
{
    const int bid = blockIdx.x;               // 256 blocks
    const int wid = (bid & 7) * 32 + (bid >> 3);
    const int mbase = (wid & 7) * 128;        // dout  (8 m-tiles)
    const int nbase = (wid >> 3) * 128;       // token (32 n-tiles)

    const int tid = threadIdx.x, lane = tid & 63, wave = tid >> 6;
    const int l31 = lane & 31, hh = lane >> 5;
    const int wm = wave >> 2;        // 0..1 -> 64 dout rows
    const int wn = wave & 3;         // 0..3 -> 32 tokens

    // LDS u16 units: A[2][2 sub][128*64] at 0, B same at 32768. 128 KB.
    __shared__ __align__(16) u16 smem[65536];

    // staging: 2048 16B-chunks per 128x128 tile per matrix; thread owns
    // p = c*512 + tid, c in {0..3}. sub = p>>10, row = (p>>3)&127,
    // slot = p&7, source chunk cg = slot ^ (row&7) (SWZ8 inverse = itself).
    size_t aoff[4], boff[4];
    #pragma unroll
    for (int c = 0; c < 4; ++c) {
        int p = c * 512 + tid;
        int sub = p >> 10;
        int row = (p >> 3) & 127;
        int cg  = (p & 7) ^ (row & 7);
        aoff[c] = (size_t)(mbase + row) * D_MODEL + sub * 64 + cg * 8;
        boff[c] = (size_t)(nbase + row) * D_MODEL + sub * 64 + cg * 8;
    }

#define OSTAGE(buf, kc)                                                             \
    do {                                                                            \
        _Pragma("unroll")                                                           \
        for (int c = 0; c < 4; ++c) {                                               \
            __builtin_amdgcn_global_load_lds(GAS(Wob + aoff[c] + (kc)),             \
                LAS(smem + (buf) * 16384 + c * 4096 + tid * 8), 16, 0, 0);          \
            __builtin_amdgcn_global_load_lds(GAS(aw + boff[c] + (kc)),              \
                LAS(smem + 32768 + (buf) * 16384 + c * 4096 + tid * 8), 16, 0, 0);  \
        }                                                                           \
    } while (0)

    OSTAGE(0, 0);

    f32x16 acc[2];
    #pragma unroll
    for (int mt = 0; mt < 2; ++mt)
        #pragma unroll
        for (int q = 0; q < 16; ++q) acc[mt][q] = 0.f;

    for (int t = 0; t < D_MODEL / 128; ++t) {
        const int cur = t & 1;
        asm volatile("s_waitcnt vmcnt(0) lgkmcnt(0)" ::: "memory");
        __builtin_amdgcn_s_barrier();
        asm volatile("" ::: "memory");
        if (t < D_MODEL / 128 - 1) OSTAGE(cur ^ 1, (t + 1) * 128);
        const u16* Ab = smem + cur * 16384;
        const u16* Bb = smem + 32768 + cur * 16384;
        #pragma unroll
        for (int kk = 0; kk < 8; ++kk) {
            const int sub = kk >> 2;            // 64-col subtile
            const int cc  = (kk & 3) * 2 + hh;  // chunk-col within subtile
            bf16x8 af[2], bfr;
            #pragma unroll
            for (int mt = 0; mt < 2; ++mt)
                af[mt] = *(const bf16x8*)&Ab[sub * 8192 + SWZ8(wm * 64 + mt * 32 + l31, cc)];
            bfr = *(const bf16x8*)&Bb[sub * 8192 + SWZ8(wn * 32 + l31, cc)];
            __builtin_amdgcn_s_setprio(1);
            #pragma unroll
            for (int mt = 0; mt < 2; ++mt)
                acc[mt] = __builtin_amdgcn_mfma_f32_32x32x16_bf16(af[mt], bfr, acc[mt], 0, 0, 0);
            __builtin_amdgcn_s_setprio(0);
        }
    }
#undef OSTAGE

    // C layout (32x32x16): col(token) = lane&31, row(dout) = (reg&3)+8*(reg>>2)+4*hh
    const int tok = nbase + wn * 32 + l31;
    float* orow = out + (size_t)tok * D_MODEL;
    #pragma unroll
    for (int mt = 0; mt < 2; ++mt)
        #pragma unroll
        for (int g = 0; g < 4; ++g) {
            const int d0 = mbase + wm * 64 + mt * 32 + 8 * g + 4 * hh;
            float4 b4 = *(const float4*)&bo[d0];
            float4 st;
            st.x = acc[mt][4 * g + 0] + b4.x;
            st.y = acc[mt][4 * g + 1] + b4.y;
            st.z = acc[mt][4 * g + 2] + b4.z;
            st.w = acc[mt][4 * g + 3] + b4.w;
            *(float4*)(orow + d0) = st;
        }
}

extern "C" void kernel_launch(void* const* d_in, const int* in_sizes, int n_in,
                              void* d_out, int out_size, void* d_ws, size_t ws_size,
                              hipStream_t stream) {
    const float* Q  = (const float*)d_in[0];
    const float* K  = (const float*)d_in[1];
    const float* V  = (const float*)d_in[2];
    const float* Wq = (const float*)d_in[3];
    const float* bq = (const float*)d_in[4];
    const float* Wk = (const float*)d_in[5];
    const float* bk = (const float*)d_in[6];
    const float* Wv = (const float*)d_in[7];
    const float* bv = (const float*)d_in[8];
    const float* Wo = (const float*)d_in[9];
    const float* bo = (const float*)d_in[10];

    const size_t NT = (size_t)NTOK * D_MODEL;    // 4M
    const size_t WN = (size_t)D_MODEL * D_MODEL; // 1M
    u16* base = (u16*)d_ws;                      // 28M u16 = 56 MB total
    u16* qw  = base;
    u16* kw  = base + NT;
    u16* vtw = base + 2 * NT;   // [1024 dout][4096 tok]
    u16* Qb  = base + 3 * NT;   // aliased by aww after proj
    u16* Kb  = base + 4 * NT;
    u16* Vb  = base + 5 * NT;
    u16* Wqb = base + 6 * NT;
    u16* Wkb = Wqb + WN;
    u16* Wvb = Wkb + WN;
    u16* Wob = Wvb + WN;
    u16* aww = Qb;              // Qb dead after proj

    convert_kernel<<<1024, 256, 0, stream>>>(Q, K, V, Wq, Wk, Wv, Wo,
                                             Qb, Kb, Vb, Wqb, Wkb, Wvb, Wob);
    proj_kernel<<<dim3(192), 512, 0, stream>>>(Qb, Kb, Vb, Wqb, Wkb, Wvb,
                                               bq, bk, bv, qw, kw, vtw);
    attn_kernel<<<dim3(S_LEN / 128, NHEAD, BATCH), 512, 0, stream>>>(qw, kw, vtw, aww);
    outproj_kernel<<<dim3(256), 512, 0, stream>>>(aww, Wob, bo, (float*)d_out);
}

// Round 7
// 209.151 us; speedup vs baseline: 1.0330x; 1.0330x over previous
//
#include <hip/hip_runtime.h>
#include <stdint.h>

#define D_MODEL 1024
#define S_LEN   2048
#define BATCH   2
#define NHEAD   16
#define DHEAD   64
#define NTOK    (BATCH * S_LEN)   // 4096

typedef unsigned short u16;
typedef __attribute__((ext_vector_type(8))) short bf16x8;
typedef __attribute__((ext_vector_type(4))) float f32x4;
typedef __attribute__((ext_vector_type(16))) float f32x16;
typedef __attribute__((ext_vector_type(2))) unsigned int u32x2;

__device__ __forceinline__ unsigned pack2bf(float lo, float hi) {
    unsigned a = __float_as_uint(lo) + 0x8000u;
    unsigned b = __float_as_uint(hi) + 0x8000u;
    return __builtin_amdgcn_perm(b, a, 0x07060302u);  // lo16=bf16(lo), hi16=bf16(hi)
}
__device__ __forceinline__ u16 f2bf1(float f) {
    return (u16)((__float_as_uint(f) + 0x8000u) >> 16);
}

#define GAS(p) ((const __attribute__((address_space(1))) void*)(p))
#define LAS(p) ((__attribute__((address_space(3))) void*)(p))
// chunk-XOR swizzled flat [rows][64] bf16 tile: u16 index of (row, chunk-col c)
#define SWZ8(row, c) (((((row) << 3) | ((c) ^ ((row) & 7)))) << 3)

// ---------------------------------------------------------------------------
// convert: fp32 -> bf16 for Q,K,V (4M each) and Wq,Wk,Wv,Wo (1M each).
// ---------------------------------------------------------------------------
__global__ __launch_bounds__(256) void convert_kernel(
    const float* __restrict__ Q, const float* __restrict__ K, const float* __restrict__ V,
    const float* __restrict__ Wq, const float* __restrict__ Wk,
    const float* __restrict__ Wv, const float* __restrict__ Wo,
    u16* __restrict__ Qb, u16* __restrict__ Kb, u16* __restrict__ Vb,
    u16* __restrict__ Wqb, u16* __restrict__ Wkb, u16* __restrict__ Wvb, u16* __restrict__ Wob)
{
    const size_t SEG = 262144;  // float4 per 1M-float quarter
    size_t start = (size_t)blockIdx.x * 4096;
    int s = (int)(start / SEG);
    const float* src; u16* dst; size_t seg0;
    if (s < 4)       { src = Q;  dst = Qb;  seg0 = 0; }
    else if (s < 8)  { src = K;  dst = Kb;  seg0 = 4 * SEG; }
    else if (s < 12) { src = V;  dst = Vb;  seg0 = 8 * SEG; }
    else if (s == 12){ src = Wq; dst = Wqb; seg0 = 12 * SEG; }
    else if (s == 13){ src = Wk; dst = Wkb; seg0 = 13 * SEG; }
    else if (s == 14){ src = Wv; dst = Wvb; seg0 = 14 * SEG; }
    else             { src = Wo; dst = Wob; seg0 = 15 * SEG; }
    size_t off = start - seg0 + threadIdx.x;
    const float4* s4 = (const float4*)src;
    #pragma unroll
    for (int k = 0; k < 16; ++k) {
        float4 x = s4[off + (size_t)k * 256];
        u32x2 p = (u32x2){pack2bf(x.x, x.y), pack2bf(x.z, x.w)};
        *(u32x2*)(dst + (off + (size_t)k * 256) * 4) = p;
    }
}

// ---------------------------------------------------------------------------
// proj: all three projections in ONE launch. 256x256 tile, BK=64, 8 waves
// (2M x 4N), mfma_f32_32x32x16_bf16, double-buffered LDS (128 KB) with one
// raw s_barrier + vmcnt(0) per K-tile; next tile's global_load_lds issued
// right after the barrier so loads fly across a full compute section.
// (R2 structure, measured 46.1 us — R3/R4 scheduling variants both
// regressed; at 1 block/CU this is the local optimum. DO NOT TOUCH.)
// XCD-chunked bijective swizzle (192 blocks = 24/XCD).
// Operand-swapped: A = W (m = dout), B = X (n = token).
//  z=0: qw[tok][dm] = (Qb@Wq^T + bq) * 0.125*log2(e)
//  z=1: kw[tok][dm] =  Kb@Wk^T + bk
//  z=2: vtw[dout][tok] = Wv@Vb^T + bv   (kv-contiguous rows for attention)
// ---------------------------------------------------------------------------
__global__ __launch_bounds__(512, 2) void proj_kernel(
    const u16* __restrict__ Qb, const u16* __restrict__ Kb, const u16* __restrict__ Vb,
    const u16* __restrict__ Wqb, const u16* __restrict__ Wkb, const u16* __restrict__ Wvb,
    const float* __restrict__ bq, const float* __restrict__ bk, const float* __restrict__ bv,
    u16* __restrict__ qw, u16* __restrict__ kw, u16* __restrict__ vtw)
{
    // 192 blocks total; bid%8 round-robins XCDs -> chunk 24 consecutive works/XCD
    const int bid = blockIdx.x;
    const int wid = (bid & 7) * 24 + (bid >> 3);
    const int z = wid >> 6;          // 0..2
    const int r = wid & 63;          // 0..63
    const int nbase = (r >> 2) * 256;   // token   (16 n-tiles)
    const int mbase = (r & 3) * 256;    // dout    (4 m-tiles)

    const u16* Ag = (z == 0) ? Wqb : (z == 1) ? Wkb : Wvb;   // [dout][din]
    const u16* Bg = (z == 0) ? Qb  : (z == 1) ? Kb  : Vb;    // [tok][din]
    const float* bias = (z == 0) ? bq : (z == 1) ? bk : bv;  // indexed by dout

    const int tid = threadIdx.x, lane = tid & 63, wave = tid >> 6;
    const int l31 = lane & 31, hh = lane >> 5;
    const int wm = wave >> 2;        // 0..1  -> 128 dout rows
    const int wn = wave & 3;         // 0..3  -> 64 tokens

    // LDS: A[2][256*64] at 0, B[2][256*64] at 32768 (u16 units). 128 KB total.
    __shared__ __align__(16) u16 smem[65536];

    // staging: 32 segments of 1 KB per matrix; wave w owns segs w*4..w*4+3.
    // chunkpos = seg*64 + lane; row = chunkpos>>3; chunk-col = (chunkpos&7)^(row&7)
    size_t aoff[4], boff[4];
    #pragma unroll
    for (int c = 0; c < 4; ++c) {
        int p = (wave * 4 + c) * 64 + lane;
        int row = p >> 3;
        int cg  = (p & 7) ^ (row & 7);
        aoff[c] = (size_t)(mbase + row) * D_MODEL + cg * 8;
        boff[c] = (size_t)(nbase + row) * D_MODEL + cg * 8;
    }

#define STAGE(buf, kc)                                                              \
    do {                                                                            \
        _Pragma("unroll")                                                           \
        for (int c = 0; c < 4; ++c) {                                               \
            __builtin_amdgcn_global_load_lds(GAS(Ag + aoff[c] + (kc)),              \
                LAS(smem + (buf) * 16384 + (wave * 4 + c) * 512), 16, 0, 0);        \
            __builtin_amdgcn_global_load_lds(GAS(Bg + boff[c] + (kc)),              \
                LAS(smem + 32768 + (buf) * 16384 + (wave * 4 + c) * 512), 16, 0, 0);\
        }                                                                           \
    } while (0)

    STAGE(0, 0);

    f32x16 acc[4][2];
    #pragma unroll
    for (int mt = 0; mt < 4; ++mt)
        #pragma unroll
        for (int nt = 0; nt < 2; ++nt)
            #pragma unroll
            for (int q = 0; q < 16; ++q) acc[mt][nt][q] = 0.f;

    for (int t = 0; t < D_MODEL / 64; ++t) {
        const int cur = t & 1;
        // wait own stage loads of tile t (flew across previous compute section)
        asm volatile("s_waitcnt vmcnt(0) lgkmcnt(0)" ::: "memory");
        __builtin_amdgcn_s_barrier();
        asm volatile("" ::: "memory");
        if (t < D_MODEL / 64 - 1) STAGE(cur ^ 1, (t + 1) * 64);
        const u16* Ab = smem + cur * 16384;
        const u16* Bb = smem + 32768 + cur * 16384;
        #pragma unroll
        for (int kk = 0; kk < 4; ++kk) {
            bf16x8 af[4], bfr[2];
            #pragma unroll
            for (int mt = 0; mt < 4; ++mt)
                af[mt] = *(const bf16x8*)&Ab[SWZ8(wm * 128 + mt * 32 + l31, kk * 2 + hh)];
            #pragma unroll
            for (int nt = 0; nt < 2; ++nt)
                bfr[nt] = *(const bf16x8*)&Bb[SWZ8(wn * 64 + nt * 32 + l31, kk * 2 + hh)];
            #pragma unroll
            for (int mt = 0; mt < 4; ++mt)
                #pragma unroll
                for (int nt = 0; nt < 2; ++nt)
                    acc[mt][nt] = __builtin_amdgcn_mfma_f32_32x32x16_bf16(af[mt], bfr[nt], acc[mt][nt], 0, 0, 0);
        }
    }
#undef STAGE

    // C layout (32x32x16): col(token) = lane&31, row(dout) = (reg&3)+8*(reg>>2)+4*hh
    if (z < 2) {
        u16* Y = z ? kw : qw;
        const float scale = z ? 1.0f : 0.18033688011112042f;  // 0.125*log2(e)
        #pragma unroll
        for (int mt = 0; mt < 4; ++mt)
            #pragma unroll
            for (int nt = 0; nt < 2; ++nt) {
                const int tok = nbase + wn * 64 + nt * 32 + l31;
                u16* yrow = Y + (size_t)tok * D_MODEL;
                #pragma unroll
                for (int g = 0; g < 4; ++g) {
                    const int d0 = mbase + wm * 128 + mt * 32 + 8 * g + 4 * hh;
                    float4 b4 = *(const float4*)&bias[d0];
                    float v0 = (acc[mt][nt][4 * g + 0] + b4.x) * scale;
                    float v1 = (acc[mt][nt][4 * g + 1] + b4.y) * scale;
                    float v2 = (acc[mt][nt][4 * g + 2] + b4.z) * scale;
                    float v3 = (acc[mt][nt][4 * g + 3] + b4.w) * scale;
                    *(u32x2*)(yrow + d0) = (u32x2){pack2bf(v0, v1), pack2bf(v2, v3)};
                }
            }
    } else {
        #pragma unroll
        for (int mt = 0; mt < 4; ++mt)
            #pragma unroll
            for (int nt = 0; nt < 2; ++nt) {
                const int tok = nbase + wn * 64 + nt * 32 + l31;
                #pragma unroll
                for (int g = 0; g < 4; ++g) {
                    const int d0 = mbase + wm * 128 + mt * 32 + 8 * g + 4 * hh;
                    #pragma unroll
                    for (int q = 0; q < 4; ++q)
                        vtw[(size_t)(d0 + q) * NTOK + tok] =
                            f2bf1(acc[mt][nt][4 * g + q] + bias[d0 + q]);
                }
            }
    }
}

// ---------------------------------------------------------------------------
// Flash attention R7: QBLK=256 -> each ds_read_b128 feeds TWO MFMAs.
// 256 blocks (1/CU), 512 threads, 8 waves = 4 q-tiles(64q) x 2 kv-halves.
// Per wave-iter: 4 K reads -> 8 QK MFMA (sc0,sc1); 32 exp2; cvt_pk+permlane;
// 4 V reads -> 8 PV MFMA (o0,o1). LDS-read demand per unit work HALVES vs
// the 128-q version (attn was LDS-throughput bound: 16 waves x 8 b128 x
// ~16cyc ~= 2050 of 3420 cyc/CU-iter). K/V staging per q-row also halves.
// XCD swizzle: all 8 q-blocks of one (h,b) on the same XCD (4 K/V panels
// = 2 MB < 4 MB L2). Fixed-max exp2 softmax; T5 setprio on MFMA clusters.
// ---------------------------------------------------------------------------
__global__ __launch_bounds__(512, 2) void attn_kernel(
    const u16* __restrict__ qw, const u16* __restrict__ kw,
    const u16* __restrict__ vtw, u16* __restrict__ aw)
{
    // 256 blocks; xcd = bid&7 hosts 32 consecutive works = 4 (h,b) groups.
    const int bid = blockIdx.x;
    const int w = (bid & 7) * 32 + (bid >> 3);   // 0..255
    const int qbase = (w & 7) * 256;             // q super-tile
    const int g = w >> 3;                        // (h,b) group 0..31
    const int h = g & 15, b = g >> 4;

    const int tid = threadIdx.x, lane = tid & 63, wave = tid >> 6;
    const int wq = wave & 3;        // q-tile (64 q rows)
    const int wk = wave >> 2;       // kv half (32 kv rows of the 64-tile)
    const int l31 = lane & 31;
    const int hh  = lane >> 5;
    const int colbase = h * DHEAD;
    const size_t qrow0 = (size_t)b * S_LEN + qbase;

    // smem (u16 offsets): Ks[buf] at buf*4096, Vs[buf] at 8192+buf*4096
    // (staging 32 KB). After the kv loop the region is reused as
    // Ored [4 qt][64 q][68] f32 (34816 u16) + Lred [4][64] f32 at 34816.
    // Total 35328 u16 = 70656 B -> 1 block/CU (grid is 1/CU anyway).
    __shared__ __align__(16) u16 smem[35328];
    #define KS_OFF(buf) ((buf) * 4096)
    #define VS_OFF(buf) (8192 + (buf) * 4096)

    // staging: one chunk per thread (512 chunks per 64x64 tile)
    const int srow = tid >> 3;
    const int scg  = (tid & 7) ^ (srow & 7);
    const size_t ksrc = ((size_t)b * S_LEN + srow) * D_MODEL + colbase + scg * 8;
    const size_t vsrc = (size_t)(colbase + srow) * NTOK + (size_t)b * S_LEN + scg * 8;

    #define STAGE_KV(buf, kv0)                                                         \
        do {                                                                           \
            __builtin_amdgcn_global_load_lds(GAS(kw + ksrc + (size_t)(kv0) * D_MODEL), \
                                             LAS(smem + KS_OFF(buf) + wave * 512), 16, 0, 0); \
            __builtin_amdgcn_global_load_lds(GAS(vtw + vsrc + (kv0)),                  \
                                             LAS(smem + VS_OFF(buf) + wave * 512), 16, 0, 0); \
        } while (0)

    // Q B-frags for both 32-q halves of this wave's 64 q rows:
    // qf[j][s]: B[k=d=16s+8hh+jj][n=q=wq*64+j*32+l31]
    bf16x8 qf0[4], qf1[4];
    {
        const u16* qp0 = qw + (qrow0 + wq * 64 + l31) * D_MODEL + colbase + hh * 8;
        const u16* qp1 = qw + (qrow0 + wq * 64 + 32 + l31) * D_MODEL + colbase + hh * 8;
        #pragma unroll
        for (int s = 0; s < 4; ++s) {
            qf0[s] = *(const bf16x8*)(qp0 + s * 16);
            qf1[s] = *(const bf16x8*)(qp1 + s * 16);
        }
    }

    STAGE_KV(0, 0);

    f32x16 o0[2], o1[2];
    #pragma unroll
    for (int dt = 0; dt < 2; ++dt)
        #pragma unroll
        for (int r = 0; r < 16; ++r) { o0[dt][r] = 0.f; o1[dt][r] = 0.f; }
    float l0 = 0.f, l1 = 0.f;

    __syncthreads();

    for (int t = 0; t < S_LEN / 64; ++t) {
        const int cur = t & 1;
        if (t + 1 < S_LEN / 64) STAGE_KV(!cur, (t + 1) * 64);   // prefetch in flight

        // S^T: 32 kv rows x 64 q cols (2 halves), C init -12 (exp2 headroom)
        f32x16 sc0, sc1;
        #pragma unroll
        for (int r = 0; r < 16; ++r) { sc0[r] = -12.f; sc1[r] = -12.f; }
        __builtin_amdgcn_s_setprio(1);
        #pragma unroll
        for (int s = 0; s < 4; ++s) {
            bf16x8 kf = *(const bf16x8*)&smem[KS_OFF(cur) + SWZ8(wk * 32 + l31, s * 2 + hh)];
            sc0 = __builtin_amdgcn_mfma_f32_32x32x16_bf16(kf, qf0[s], sc0, 0, 0, 0);
            sc1 = __builtin_amdgcn_mfma_f32_32x32x16_bf16(kf, qf1[s], sc1, 0, 0, 0);
        }
        __builtin_amdgcn_s_setprio(0);

        // p = exp2(s); x*[gg] covers kv_local = 8gg + 4hh + {0..3}
        unsigned x0[4][2], x1[4][2];
        #pragma unroll
        for (int gg = 0; gg < 4; ++gg) {
            float p0 = __builtin_amdgcn_exp2f(sc0[4 * gg + 0]);
            float p1 = __builtin_amdgcn_exp2f(sc0[4 * gg + 1]);
            float p2 = __builtin_amdgcn_exp2f(sc0[4 * gg + 2]);
            float p3 = __builtin_amdgcn_exp2f(sc0[4 * gg + 3]);
            l0 += (p0 + p1) + (p2 + p3);
            asm("v_cvt_pk_bf16_f32 %0, %1, %2" : "=v"(x0[gg][0]) : "v"(p0), "v"(p1));
            asm("v_cvt_pk_bf16_f32 %0, %1, %2" : "=v"(x0[gg][1]) : "v"(p2), "v"(p3));
            float q0 = __builtin_amdgcn_exp2f(sc1[4 * gg + 0]);
            float q1 = __builtin_amdgcn_exp2f(sc1[4 * gg + 1]);
            float q2 = __builtin_amdgcn_exp2f(sc1[4 * gg + 2]);
            float q3 = __builtin_amdgcn_exp2f(sc1[4 * gg + 3]);
            l1 += (q0 + q1) + (q2 + q3);
            asm("v_cvt_pk_bf16_f32 %0, %1, %2" : "=v"(x1[gg][0]) : "v"(q0), "v"(q1));
            asm("v_cvt_pk_bf16_f32 %0, %1, %2" : "=v"(x1[gg][1]) : "v"(q2), "v"(q3));
        }

        // PV: B-frag(sp) covers kv_local = 16sp + 8hh + j; one permlane swap
        // yields both P-frag words. Each V read feeds BOTH q-halves' MFMAs.
        #pragma unroll
        for (int sp = 0; sp < 2; ++sp) {
            unsigned a0 = x0[2 * sp][0], b0 = x0[2 * sp + 1][0];
            unsigned a1 = x0[2 * sp][1], b1 = x0[2 * sp + 1][1];
            asm("v_permlane32_swap_b32 %0, %1" : "+v"(a0), "+v"(b0));
            asm("v_permlane32_swap_b32 %0, %1" : "+v"(a1), "+v"(b1));
            union { unsigned u[4]; bf16x8 v; } pf0;
            pf0.u[0] = a0; pf0.u[1] = a1; pf0.u[2] = b0; pf0.u[3] = b1;
            unsigned c0 = x1[2 * sp][0], d0 = x1[2 * sp + 1][0];
            unsigned c1 = x1[2 * sp][1], d1 = x1[2 * sp + 1][1];
            asm("v_permlane32_swap_b32 %0, %1" : "+v"(c0), "+v"(d0));
            asm("v_permlane32_swap_b32 %0, %1" : "+v"(c1), "+v"(d1));
            union { unsigned u[4]; bf16x8 v; } pf1;
            pf1.u[0] = c0; pf1.u[1] = c1; pf1.u[2] = d0; pf1.u[3] = d1;
            __builtin_amdgcn_s_setprio(1);
            #pragma unroll
            for (int dt = 0; dt < 2; ++dt) {
                bf16x8 vf = *(const bf16x8*)&smem[VS_OFF(cur) + SWZ8(dt * 32 + l31, wk * 4 + sp * 2 + hh)];
                o0[dt] = __builtin_amdgcn_mfma_f32_32x32x16_bf16(vf, pf0.v, o0[dt], 0, 0, 0);
                o1[dt] = __builtin_amdgcn_mfma_f32_32x32x16_bf16(vf, pf1.v, o1[dt], 0, 0, 0);
            }
            __builtin_amdgcn_s_setprio(0);
        }

        __syncthreads();   // drains prefetch + protects both staging buffers
    }

    // merge lane halves of l (each covers complementary kv groups)
    l0 += __shfl_xor(l0, 32);
    l1 += __shfl_xor(l1, 32);

    // cross kv-half reduction through LDS (staging region is dead now)
    float* Ored = (float*)smem;                   // [4 qt][64 q][68] f32
    float* Lred = (float*)(smem + 34816);         // [4 qt][64 q] f32
    float* op0 = Ored + ((size_t)wq * 64 + l31) * 68;
    float* op1 = Ored + ((size_t)wq * 64 + 32 + l31) * 68;
    if (wk == 1) {
        #pragma unroll
        for (int dt = 0; dt < 2; ++dt)
            #pragma unroll
            for (int gg = 0; gg < 4; ++gg) {
                *(f32x4*)(op0 + dt * 32 + 8 * gg + 4 * hh) =
                    (f32x4){o0[dt][4 * gg + 0], o0[dt][4 * gg + 1], o0[dt][4 * gg + 2], o0[dt][4 * gg + 3]};
                *(f32x4*)(op1 + dt * 32 + 8 * gg + 4 * hh) =
                    (f32x4){o1[dt][4 * gg + 0], o1[dt][4 * gg + 1], o1[dt][4 * gg + 2], o1[dt][4 * gg + 3]};
            }
        if (hh == 0) {
            Lred[wq * 64 + l31] = l0;
            Lred[wq * 64 + 32 + l31] = l1;
        }
    }
    __syncthreads();
    if (wk == 0) {
        l0 += Lred[wq * 64 + l31];
        l1 += Lred[wq * 64 + 32 + l31];
        float inv0 = 1.0f / l0, inv1 = 1.0f / l1;
        size_t orow0 = (qrow0 + wq * 64 + l31) * D_MODEL + colbase;
        size_t orow1 = (qrow0 + wq * 64 + 32 + l31) * D_MODEL + colbase;
        #pragma unroll
        for (int dt = 0; dt < 2; ++dt)
            #pragma unroll
            for (int gg = 0; gg < 4; ++gg) {
                f32x4 add0 = *(const f32x4*)(op0 + dt * 32 + 8 * gg + 4 * hh);
                f32x4 add1 = *(const f32x4*)(op1 + dt * 32 + 8 * gg + 4 * hh);
                float v0 = (o0[dt][4 * gg + 0] + add0[0]) * inv0;
                float v1 = (o0[dt][4 * gg + 1] + add0[1]) * inv0;
                float v2 = (o0[dt][4 * gg + 2] + add0[2]) * inv0;
                float v3 = (o0[dt][4 * gg + 3] + add0[3]) * inv0;
                *(u32x2*)(aw + orow0 + dt * 32 + 8 * gg + 4 * hh) =
                    (u32x2){pack2bf(v0, v1), pack2bf(v2, v3)};
                float u0 = (o1[dt][4 * gg + 0] + add1[0]) * inv1;
                float u1 = (o1[dt][4 * gg + 1] + add1[1]) * inv1;
                float u2 = (o1[dt][4 * gg + 2] + add1[2]) * inv1;
                float u3 = (o1[dt][4 * gg + 3] + add1[3]) * inv1;
                *(u32x2*)(aw + orow1 + dt * 32 + 8 * gg + 4 * hh) =
                    (u32x2){pack2bf(u0, u1), pack2bf(u2, u3)};
            }
    }
    #undef STAGE_KV
    #undef KS_OFF
    #undef VS_OFF
}

// ---------------------------------------------------------------------------
// outproj: out[tok][dm] = aw @ Wo^T + bo (fp32 out). R5 structure (BK=64,
// 64 KB LDS — R6's BK=128 regressed slightly, reverted): 128x128 tile,
// 256 blocks (1/CU), 512 threads / 8 waves (2M x 4N), 32x32x16 MFMA,
// double-buffered LDS, one vmcnt(0)+s_barrier per K-tile with next tile's
// loads issued right after the barrier. XCD-chunked.
// Operand-swapped: A = Wo (m = dout), B = aw (n = token).
// ---------------------------------------------------------------------------
__global__ __launch_bounds__(512, 2) void outproj_kernel(
    const u16* __restrict__ aw, const u16* __restrict__ Wob,
    const float* __restrict__ bo, float* __restrict__ out)
{
    const int bid = blockIdx.x;               // 256 blocks
    const int wid = (bid & 7) * 32 + (bid >> 3);
    const int mbase = (wid & 7) * 128;        // dout  (8 m-tiles)
    const int nbase = (wid >> 3) * 128;       // token (32 n-tiles)

    const int tid = threadIdx.x, lane = tid & 63, wave = tid >> 6;
    const int l31 = lane & 31, hh = lane >> 5;
    const int wm = wave >> 2;        // 0..1 -> 64 dout rows
    const int wn = wave & 3;         // 0..3 -> 32 tokens

    // LDS u16 units: A[2][128*64] at 0, B[2][128*64] at 16384. 64 KB total.
    __shared__ __align__(16) u16 smem[32768];

    // staging: 1024 16B-chunks per 128x64 tile; thread owns chunks
    // p = c*512 + tid, c in {0,1}. row = p>>3, cg = (p&7)^(row&7).
    size_t aoff[2], boff[2];
    #pragma unroll
    for (int c = 0; c < 2; ++c) {
        int p = c * 512 + tid;
        int row = p >> 3;
        int cg  = (p & 7) ^ (row & 7);
        aoff[c] = (size_t)(mbase + row) * D_MODEL + cg * 8;
        boff[c] = (size_t)(nbase + row) * D_MODEL + cg * 8;
    }

#define OSTAGE(buf, kc)                                                             \
    do {                                                                            \
        _Pragma("unroll")                                                           \
        for (int c = 0; c < 2; ++c) {                                               \
            __builtin_amdgcn_global_load_lds(GAS(Wob + aoff[c] + (kc)),             \
                LAS(smem + (buf) * 8192 + c * 4096 + wave * 512), 16, 0, 0);        \
            __builtin_amdgcn_global_load_lds(GAS(aw + boff[c] + (kc)),              \
                LAS(smem + 16384 + (buf) * 8192 + c * 4096 + wave * 512), 16, 0, 0);\
        }                                                                           \
    } while (0)

    OSTAGE(0, 0);

    f32x16 acc[2];
    #pragma unroll
    for (int mt = 0; mt < 2; ++mt)
        #pragma unroll
        for (int q = 0; q < 16; ++q) acc[mt][q] = 0.f;

    for (int t = 0; t < D_MODEL / 64; ++t) {
        const int cur = t & 1;
        asm volatile("s_waitcnt vmcnt(0) lgkmcnt(0)" ::: "memory");
        __builtin_amdgcn_s_barrier();
        asm volatile("" ::: "memory");
        if (t < D_MODEL / 64 - 1) OSTAGE(cur ^ 1, (t + 1) * 64);
        const u16* Ab = smem + cur * 8192;
        const u16* Bb = smem + 16384 + cur * 8192;
        #pragma unroll
        for (int kk = 0; kk < 4; ++kk) {
            bf16x8 af[2], bfr;
            #pragma unroll
            for (int mt = 0; mt < 2; ++mt)
                af[mt] = *(const bf16x8*)&Ab[SWZ8(wm * 64 + mt * 32 + l31, kk * 2 + hh)];
            bfr = *(const bf16x8*)&Bb[SWZ8(wn * 32 + l31, kk * 2 + hh)];
            __builtin_amdgcn_s_setprio(1);
            #pragma unroll
            for (int mt = 0; mt < 2; ++mt)
                acc[mt] = __builtin_amdgcn_mfma_f32_32x32x16_bf16(af[mt], bfr, acc[mt], 0, 0, 0);
            __builtin_amdgcn_s_setprio(0);
        }
    }
#undef OSTAGE

    // C layout (32x32x16): col(token) = lane&31, row(dout) = (reg&3)+8*(reg>>2)+4*hh
    const int tok = nbase + wn * 32 + l31;
    float* orow = out + (size_t)tok * D_MODEL;
    #pragma unroll
    for (int mt = 0; mt < 2; ++mt)
        #pragma unroll
        for (int g = 0; g < 4; ++g) {
            const int d0 = mbase + wm * 64 + mt * 32 + 8 * g + 4 * hh;
            float4 b4 = *(const float4*)&bo[d0];
            float4 st;
            st.x = acc[mt][4 * g + 0] + b4.x;
            st.y = acc[mt][4 * g + 1] + b4.y;
            st.z = acc[mt][4 * g + 2] + b4.z;
            st.w = acc[mt][4 * g + 3] + b4.w;
            *(float4*)(orow + d0) = st;
        }
}

extern "C" void kernel_launch(void* const* d_in, const int* in_sizes, int n_in,
                              void* d_out, int out_size, void* d_ws, size_t ws_size,
                              hipStream_t stream) {
    const float* Q  = (const float*)d_in[0];
    const float* K  = (const float*)d_in[1];
    const float* V  = (const float*)d_in[2];
    const float* Wq = (const float*)d_in[3];
    const float* bq = (const float*)d_in[4];
    const float* Wk = (const float*)d_in[5];
    const float* bk = (const float*)d_in[6];
    const float* Wv = (const float*)d_in[7];
    const float* bv = (const float*)d_in[8];
    const float* Wo = (const float*)d_in[9];
    const float* bo = (const float*)d_in[10];

    const size_t NT = (size_t)NTOK * D_MODEL;    // 4M
    const size_t WN = (size_t)D_MODEL * D_MODEL; // 1M
    u16* base = (u16*)d_ws;                      // 28M u16 = 56 MB total
    u16* qw  = base;
    u16* kw  = base + NT;
    u16* vtw = base + 2 * NT;   // [1024 dout][4096 tok]
    u16* Qb  = base + 3 * NT;   // aliased by aww after proj
    u16* Kb  = base + 4 * NT;
    u16* Vb  = base + 5 * NT;
    u16* Wqb = base + 6 * NT;
    u16* Wkb = Wqb + WN;
    u16* Wvb = Wkb + WN;
    u16* Wob = Wvb + WN;
    u16* aww = Qb;              // Qb dead after proj

    convert_kernel<<<1024, 256, 0, stream>>>(Q, K, V, Wq, Wk, Wv, Wo,
                                             Qb, Kb, Vb, Wqb, Wkb, Wvb, Wob);
    proj_kernel<<<dim3(192), 512, 0, stream>>>(Qb, Kb, Vb, Wqb, Wkb, Wvb,
                                               bq, bk, bv, qw, kw, vtw);
    attn_kernel<<<dim3(256), 512, 0, stream>>>(qw, kw, vtw, aww);
    outproj_kernel<<<dim3(256), 512, 0, stream>>>(aww, Wob, bo, (float*)d_out);
}